// Round 8
// baseline (164.179 us; speedup 1.0000x reference)
//
#include <hip/hip_runtime.h>
#include <hip/hip_fp16.h>
#include <stdint.h>

// ---- types ----
typedef _Float16 h16;
typedef _Float16 h16x8 __attribute__((ext_vector_type(8)));
typedef float f32x4 __attribute__((ext_vector_type(4)));

#define BB 4
#define SS 2048
#define DD 1024

__device__ __forceinline__ void gload16(const void* g, void* l) {
    __builtin_amdgcn_global_load_lds(
        (const __attribute__((address_space(1))) uint32_t*)g,
        (__attribute__((address_space(3))) uint32_t*)l, 16, 0, 0);
}

// ==== fused-convert GEMM: fp32 inputs, fp16 MFMA ====
// C[m][n] = oscale * sum_k A[m][k]*B[n][k], A,B fp32 row-major along K.
// 128x128 tile, 4 waves (2Mx2N), 256 thr, 64KB LDS -> 2 blocks/CU (m114 desync).
// Staging is reg-based (T14 issue-early/write-late): global float4 loads for
// tile G+1 issued BEFORE tile G's compute; after compute, vmcnt(0) + cvt +
// swizzled ds_write_b128. Swizzle on WRITE side + READ side (rule 21);
// global reads are plain coalesced (32B/lane row segments).
// This deletes the standalone fp32->fp16 pass (its 150MB of traffic) entirely.
template<bool F32OUT>
__global__ __launch_bounds__(256, 2) void gemm_f32(
    const float* __restrict__ A, const float* __restrict__ B, void* __restrict__ Cv,
    int lda, int ldb, int ldc, int K, int tilesN, int tilesMN,
    long long aBatch, long long bBatch, long long cBatch, float oscale)
{
    constexpr int ABYTES = 128 * 128;    // fp16 bytes per matrix per K-tile
    constexpr int BUFB   = 2 * ABYTES;

    __shared__ __align__(1024) char lds[2 * BUFB];   // 64 KB

    const int tid = threadIdx.x;
    const int nwg = gridDim.x;           // %8==0 for all launches here
    const int bid = blockIdx.x;
    const int wgid = (bid & 7) * (nwg >> 3) + (bid >> 3);   // XCD swizzle
    const int bb  = wgid / tilesMN;
    const int rem = wgid % tilesMN;
    const int tm = rem / tilesN, tn = rem % tilesN;
    const int row0 = tm * 128, col0 = tn * 128;

    const float* Ab = A + (long long)bb * aBatch;
    const float* Bb = B + (long long)bb * bBatch;

    const int lane = tid & 63, wid = tid >> 6;
    const int wm = wid >> 1, wn = wid & 1;     // 2M x 2N, wave tile 64x64
    const int frow = lane & 15, kq = lane >> 4;
    const int rr = tid >> 3, gg = tid & 7;     // staging map: row rr(+32p), granule gg

    const int NT = K >> 6;

    f32x4 acc[4][4];
#pragma unroll
    for (int m = 0; m < 4; ++m)
#pragma unroll
        for (int n = 0; n < 4; ++n) acc[m][n] = (f32x4){0.f, 0.f, 0.f, 0.f};

    char* l0 = (char*)lds;

    float4 la[8], lb[8];
    // issue 16 float4 loads for K-tile kt (A,B 128x64 fp32 each)
    auto LOADS = [&](int kt) {
#pragma unroll
        for (int p = 0; p < 4; ++p) {
            int r = p * 32 + rr;
            const float* pa = Ab + (size_t)(row0 + r) * lda + kt + gg * 8;
            la[2 * p]     = *(const float4*)pa;
            la[2 * p + 1] = *(const float4*)(pa + 4);
            const float* pb = Bb + (size_t)(col0 + r) * ldb + kt + gg * 8;
            lb[2 * p]     = *(const float4*)pb;
            lb[2 * p + 1] = *(const float4*)(pb + 4);
        }
    };
    // convert + swizzled LDS write: slot s = gg ^ (r&7) holds cols [gg*8, gg*8+8)
    auto CVTWRITE = [&](int buf) {
#pragma unroll
        for (int p = 0; p < 4; ++p) {
            int r = p * 32 + rr;
            int s = gg ^ (r & 7);
            union { int4 i4; h16 h[8]; } ua, ub;
            float4 x = la[2 * p], y = la[2 * p + 1];
            ua.h[0] = (h16)x.x; ua.h[1] = (h16)x.y; ua.h[2] = (h16)x.z; ua.h[3] = (h16)x.w;
            ua.h[4] = (h16)y.x; ua.h[5] = (h16)y.y; ua.h[6] = (h16)y.z; ua.h[7] = (h16)y.w;
            x = lb[2 * p]; y = lb[2 * p + 1];
            ub.h[0] = (h16)x.x; ub.h[1] = (h16)x.y; ub.h[2] = (h16)x.z; ub.h[3] = (h16)x.w;
            ub.h[4] = (h16)y.x; ub.h[5] = (h16)y.y; ub.h[6] = (h16)y.z; ub.h[7] = (h16)y.w;
            *(int4*)(l0 + buf * BUFB + (r * 8 + s) * 16) = ua.i4;
            *(int4*)(l0 + buf * BUFB + ABYTES + (r * 8 + s) * 16) = ub.i4;
        }
    };
    auto READ_A = [&](int buf, h16x8 (&af)[4][2]) {
#pragma unroll
        for (int mm = 0; mm < 4; ++mm)
#pragma unroll
            for (int ks = 0; ks < 2; ++ks) {
                int r = wm * 64 + mm * 16 + frow;
                int s = (ks * 4 + kq) ^ (r & 7);
                af[mm][ks] = *(const h16x8*)(l0 + buf * BUFB + (r * 8 + s) * 16);
            }
    };
    auto READ_B = [&](int buf, h16x8 (&bf)[4][2]) {
#pragma unroll
        for (int nn = 0; nn < 4; ++nn)
#pragma unroll
            for (int ks = 0; ks < 2; ++ks) {
                int r = wn * 64 + nn * 16 + frow;
                int s = (ks * 4 + kq) ^ (r & 7);
                bf[nn][ks] = *(const h16x8*)(l0 + buf * BUFB + ABYTES + (r * 8 + s) * 16);
            }
    };

    // ---- prologue: tile 0 through regs into buf0
    LOADS(0);
    asm volatile("s_waitcnt vmcnt(0)" ::: "memory");
    CVTWRITE(0);
    asm volatile("s_waitcnt lgkmcnt(0)" ::: "memory");
    __builtin_amdgcn_s_barrier();

    for (int G = 0; G < NT; ++G) {
        const int bufR = G & 1;
        if (G + 1 < NT) LOADS((G + 1) << 6);   // issue early: hidden under reads+MFMA
        h16x8 af[4][2], bf[4][2];
        READ_A(bufR, af);
        READ_B(bufR, bf);
        __builtin_amdgcn_s_setprio(1);
#pragma unroll
        for (int ks = 0; ks < 2; ++ks)
#pragma unroll
            for (int mm = 0; mm < 4; ++mm)
#pragma unroll
                for (int nn = 0; nn < 4; ++nn)
                    acc[mm][nn] = __builtin_amdgcn_mfma_f32_16x16x32_f16(
                        af[mm][ks], bf[nn][ks], acc[mm][nn], 0, 0, 0);
        __builtin_amdgcn_s_setprio(0);
        if (G + 1 < NT) {
            // write-late: loads arrived; all waves done reading buf^1 (iter G-1)
            asm volatile("s_waitcnt vmcnt(0) lgkmcnt(0)" ::: "memory");
            __builtin_amdgcn_s_barrier();
            CVTWRITE(bufR ^ 1);
            asm volatile("s_waitcnt lgkmcnt(0)" ::: "memory");
            __builtin_amdgcn_s_barrier();
        }
    }

    // ---- epilogue: C/D layout col=lane&15, row=(lane>>4)*4+j; oscale folded here
    const int erow = row0 + wm * 64 + (lane >> 4) * 4;
    const int ecol = col0 + wn * 64 + (lane & 15);
    if (F32OUT) {
        float* C = (float*)Cv + (long long)bb * cBatch;
#pragma unroll
        for (int m = 0; m < 4; ++m)
#pragma unroll
            for (int n = 0; n < 4; ++n)
#pragma unroll
                for (int j = 0; j < 4; ++j)
                    C[(size_t)(erow + m * 16 + j) * ldc + (ecol + n * 16)] = acc[m][n][j] * oscale;
    } else {
        h16* C = (h16*)Cv + (long long)bb * cBatch;
#pragma unroll
        for (int m = 0; m < 4; ++m)
#pragma unroll
            for (int n = 0; n < 4; ++n)
#pragma unroll
                for (int j = 0; j < 4; ++j)
                    C[(size_t)(erow + m * 16 + j) * ldc + (ecol + n * 16)] = (h16)(acc[m][n][j] * oscale);
    }
}

// ==== fp16 GEMM (unchanged round-6 winner): used for GEMM3 ====
// 2-phase counted-vmcnt ledger, gload_lds staging, 128x128, 2 blocks/CU.
template<bool F32OUT>
__global__ __launch_bounds__(256, 2) void gemm2p_sm(
    const h16* __restrict__ A, const h16* __restrict__ B, void* __restrict__ Cv,
    int lda, int ldb, int ldc, int K, int tilesN, int tilesMN,
    long long aBatch, long long bBatch, long long cBatch)
{
    constexpr int ABYTES = 128 * 128;
    constexpr int BBYTES = 128 * 128;
    constexpr int BUFB   = ABYTES + BBYTES;

    __shared__ __align__(1024) char lds[2 * BUFB];   // 64 KB

    const int tid = threadIdx.x;
    const int nwg = gridDim.x;
    const int bid = blockIdx.x;
    const int wgid = (bid & 7) * (nwg >> 3) + (bid >> 3);
    const int bb  = wgid / tilesMN;
    const int rem = wgid % tilesMN;
    const int tm = rem / tilesN, tn = rem % tilesN;
    const int row0 = tm * 128, col0 = tn * 128;

    const h16* Ab = A + (long long)bb * aBatch;
    const h16* Bb = B + (long long)bb * bBatch;

    const int lane = tid & 63, wid = tid >> 6;
    const int wm = wid >> 1, wn = wid & 1;
    const int frow = lane & 15, kq = lane >> 4;

    const int NT = K >> 6;

    f32x4 acc[4][4];
#pragma unroll
    for (int m = 0; m < 4; ++m)
#pragma unroll
        for (int n = 0; n < 4; ++n) acc[m][n] = (f32x4){0.f, 0.f, 0.f, 0.f};

    char* l0 = (char*)lds;

    auto STAGE_B = [&](int kt, int buf) {
#pragma unroll
        for (int i = 0; i < 4; ++i) {
            int d = i * 256 + tid;
            int s = d & 7, r = d >> 3;
            int gg = s ^ (r & 7);
            gload16(Bb + (size_t)(col0 + r) * ldb + kt + gg * 8,
                    l0 + buf * BUFB + ABYTES + (r * 8 + s) * 16);
        }
    };
    auto STAGE_AH = [&](int kt, int buf, int mh) {
#pragma unroll
        for (int i = 0; i < 2; ++i) {
            int d = i * 256 + tid;
            int s = d & 7, hr = d >> 3;
            int r = ((hr & ~31) << 1) + mh * 32 + (hr & 31);
            int gg = s ^ (r & 7);
            gload16(Ab + (size_t)(row0 + r) * lda + kt + gg * 8,
                    l0 + buf * BUFB + (r * 8 + s) * 16);
        }
    };
    auto READ_A = [&](int buf, int mh, h16x8 (&af)[2][2]) {
#pragma unroll
        for (int mm = 0; mm < 2; ++mm)
#pragma unroll
            for (int ks = 0; ks < 2; ++ks) {
                int r = wm * 64 + (mh * 2 + mm) * 16 + frow;
                int s = (ks * 4 + kq) ^ (r & 7);
                af[mm][ks] = *(const h16x8*)(l0 + buf * BUFB + (r * 8 + s) * 16);
            }
    };
    auto READ_B = [&](int buf, h16x8 (&bf)[4][2]) {
#pragma unroll
        for (int nn = 0; nn < 4; ++nn)
#pragma unroll
            for (int ks = 0; ks < 2; ++ks) {
                int r = wn * 64 + nn * 16 + frow;
                int s = (ks * 4 + kq) ^ (r & 7);
                bf[nn][ks] = *(const h16x8*)(l0 + buf * BUFB + ABYTES + (r * 8 + s) * 16);
            }
    };
    auto MFMA_H = [&](int mh, h16x8 (&af)[2][2], h16x8 (&bf)[4][2]) {
        __builtin_amdgcn_s_setprio(1);
#pragma unroll
        for (int ks = 0; ks < 2; ++ks)
#pragma unroll
            for (int mm = 0; mm < 2; ++mm)
#pragma unroll
                for (int nn = 0; nn < 4; ++nn)
                    acc[mh * 2 + mm][nn] =
                        __builtin_amdgcn_mfma_f32_16x16x32_f16(
                            af[mm][ks], bf[nn][ks], acc[mh * 2 + mm][nn], 0, 0, 0);
        __builtin_amdgcn_s_setprio(0);
    };

    STAGE_B(0, 0); STAGE_AH(0, 0, 0); STAGE_AH(0, 0, 1);
    asm volatile("s_waitcnt vmcnt(2)" ::: "memory");
    __builtin_amdgcn_s_barrier();

    h16x8 af[2][2], bf[4][2];

    for (int G = 0; G < NT; ++G) {
        const int buf = G & 1;
        const int kt1 = (G + 1) << 6;
        if (G + 1 < NT) {
            STAGE_B(kt1, buf ^ 1);
            STAGE_AH(kt1, buf ^ 1, 0);
            STAGE_AH(kt1, buf ^ 1, 1);
        }
        READ_A(buf, 0, af);
        READ_B(buf, bf);
        MFMA_H(0, af, bf);
        if (G + 1 < NT) asm volatile("s_waitcnt vmcnt(8)" ::: "memory");
        else            asm volatile("s_waitcnt vmcnt(0)" ::: "memory");
        __builtin_amdgcn_s_barrier();
        READ_A(buf, 1, af);
        MFMA_H(1, af, bf);
        if (G + 1 >= NT) break;
        asm volatile("s_waitcnt vmcnt(2)" ::: "memory");
        __builtin_amdgcn_s_barrier();
    }

    const int erow = row0 + wm * 64 + (lane >> 4) * 4;
    const int ecol = col0 + wn * 64 + (lane & 15);
    if (F32OUT) {
        float* C = (float*)Cv + (long long)bb * cBatch;
#pragma unroll
        for (int m = 0; m < 4; ++m)
#pragma unroll
            for (int n = 0; n < 4; ++n)
#pragma unroll
                for (int j = 0; j < 4; ++j)
                    C[(size_t)(erow + m * 16 + j) * ldc + (ecol + n * 16)] = acc[m][n][j];
    } else {
        h16* C = (h16*)Cv + (long long)bb * cBatch;
#pragma unroll
        for (int m = 0; m < 4; ++m)
#pragma unroll
            for (int n = 0; n < 4; ++n)
#pragma unroll
                for (int j = 0; j < 4; ++j)
                    C[(size_t)(erow + m * 16 + j) * ldc + (ecol + n * 16)] = (h16)acc[m][n][j];
    }
}

// ---- row softmax, in place on fp16 rows of length 2048; one block per row ----
__global__ __launch_bounds__(256) void softmax_rows(h16* __restrict__ buf) {
    const int row = blockIdx.x;
    h16* rp = buf + (size_t)row * 2048;
    const int t = threadIdx.x;
    const int lane = t & 63, wid = t >> 6;

    union { int4 i4; h16 h[8]; } u;
    u.i4 = ((const int4*)rp)[t];
    float f[8];
#pragma unroll
    for (int j = 0; j < 8; ++j) f[j] = (float)u.h[j];

    float m = f[0];
#pragma unroll
    for (int j = 1; j < 8; ++j) m = fmaxf(m, f[j]);
#pragma unroll
    for (int off = 32; off; off >>= 1) m = fmaxf(m, __shfl_xor(m, off));

    __shared__ float smax[4];
    __shared__ float ssum[4];
    if (lane == 0) smax[wid] = m;
    __syncthreads();
    m = fmaxf(fmaxf(smax[0], smax[1]), fmaxf(smax[2], smax[3]));

    float s = 0.f;
#pragma unroll
    for (int j = 0; j < 8; ++j) { f[j] = __expf(f[j] - m); s += f[j]; }
#pragma unroll
    for (int off = 32; off; off >>= 1) s += __shfl_xor(s, off);
    if (lane == 0) ssum[wid] = s;
    __syncthreads();
    float inv = 1.0f / (ssum[0] + ssum[1] + ssum[2] + ssum[3]);

#pragma unroll
    for (int j = 0; j < 8; ++j) u.h[j] = (h16)(f[j] * inv);
    ((int4*)rp)[t] = u.i4;
}

extern "C" void kernel_launch(void* const* d_in, const int* in_sizes, int n_in,
                              void* d_out, int out_size, void* d_ws, size_t ws_size,
                              hipStream_t stream) {
    (void)in_sizes; (void)n_in; (void)out_size; (void)ws_size;
    const float* q = (const float*)d_in[0];
    const float* k = (const float*)d_in[1];
    const float* v = (const float*)d_in[2];
    const float* w = (const float*)d_in[3];
    float* out = (float*)d_out;

    h16* vpT = (h16*)d_ws;                        // 16 MB fp16 [1024][8192]
    h16* sc  = vpT + (size_t)DD * BB * SS;        // 33.5 MB fp16 scores/P

    // 1) GEMM1 (fused cvt): scores[b][q][k] = 0.125 * sum_d q[b,q,d]*k[b,k,d]
    //    M=N=2048, K=1024 per batch; 128^2 tiles: 16x16x4 = 1024 wgs
    gemm_f32<false><<<1024, 256, 0, stream>>>(
        q, k, (void*)sc, DD, DD, SS, DD, /*tilesN=*/16, /*tilesMN=*/256,
        (long long)SS * DD, (long long)SS * DD, (long long)SS * SS, 0.125f);

    // 2) softmax rows in place
    softmax_rows<<<BB * SS, 256, 0, stream>>>(sc);

    // 3) GEMM2 (fused cvt): vpT[e][s] = sum_d W[e,d]*V[s,d]; M=1024, N=8192, K=1024
    //    128^2 tiles: 8x64 = 512 wgs
    gemm_f32<false><<<512, 256, 0, stream>>>(
        w, v, (void*)vpT, DD, DD, BB * SS, DD, /*tilesN=*/64, /*tilesMN=*/512,
        0LL, 0LL, 0LL, 1.0f);

    // 4) GEMM3: Y[b][q][e] = sum_k P[b,q,k]*vpT[e, b*2048+k];
    //    M=2048/batch, N=1024, K=2048. 128^2 tiles: 16x8x4 = 512 wgs
    gemm2p_sm<true><<<512, 256, 0, stream>>>(
        sc, vpT, (void*)out, SS, BB * SS, DD, SS, /*tilesN=*/8, /*tilesMN=*/128,
        (long long)SS * SS, (long long)SS, (long long)SS * DD);
}

// Round 9
// 146.921 us; speedup vs baseline: 1.1175x; 1.1175x over previous
//
#include <hip/hip_runtime.h>
#include <hip/hip_fp16.h>
#include <stdint.h>

// ---- types ----
typedef _Float16 h16;
typedef _Float16 h16x8 __attribute__((ext_vector_type(8)));
typedef float f32x16 __attribute__((ext_vector_type(16)));

#define BB 4
#define SS 2048
#define DD 1024

// epilogue modes
#define EPI_H16 0   // store fp16 C
#define EPI_EXP 1   // store fp16 exp(C - 16)   (unnormalized softmax numerator)
#define EPI_DIV 2   // store fp32 C * rsum[row] (rsum holds reciprocal row sums)

__device__ __forceinline__ void gload16(const void* g, void* l) {
    __builtin_amdgcn_global_load_lds(
        (const __attribute__((address_space(1))) uint32_t*)g,
        (__attribute__((address_space(3))) uint32_t*)l, 16, 0, 0);
}

// ---- fused fp32 -> fp16 convert; every instruction wave-coalesced ----
__global__ __launch_bounds__(256) void cvt_all(
    const float* __restrict__ q, const float* __restrict__ k,
    const float* __restrict__ v, const float* __restrict__ w,
    h16* __restrict__ qh, h16* __restrict__ kh,
    h16* __restrict__ vh, h16* __restrict__ wh) {
    int b = blockIdx.x;
    const float* src; h16* dst; float sc = 1.0f;
    if (b < 2048)      { src = q; dst = qh; sc = 0.125f; }
    else if (b < 4096) { src = k; dst = kh; b -= 2048; }
    else if (b < 6144) { src = v; dst = vh; b -= 4096; }
    else               { src = w; dst = wh; b -= 6144; }
    size_t base = (size_t)b * 1024 + threadIdx.x;   // float4 index
#pragma unroll
    for (int i = 0; i < 4; ++i) {
        size_t g = base + (size_t)i * 256;
        float4 a = ((const float4*)src)[g];
        union { int2 i2; h16 h[4]; } u;
        u.h[0] = (h16)(a.x * sc); u.h[1] = (h16)(a.y * sc);
        u.h[2] = (h16)(a.z * sc); u.h[3] = (h16)(a.w * sc);
        ((int2*)dst)[g] = u.i2;
    }
}

// ==== big GEMM: BM=256 BN=256, 8 waves (2Mx4N), 512 thr, 128KB LDS ====
// 32x32x16 f16 MFMA (m119: +15% FLOP/cyc vs 16x16x32, half the instructions).
// A/B frag: row|col = lane&31, k = (lane>>5)*8 + e (contiguous b128 read).
// C/D: col=lane&31, row=(reg&3)+8*(reg>>2)+4*(lane>>5)  [m74/m101].
// 2-phase counted-vmcnt ledger (round-5/6 proven): stage 8 loads/K-tile,
// mid vmcnt(8), end vmcnt(2); T2 granule swizzle both-sides.
template<int EPI>
__global__ __launch_bounds__(512, 2) void gemm32_big(
    const h16* __restrict__ A, const h16* __restrict__ B, void* __restrict__ Cv,
    int lda, int ldb, int ldc, int K, int tilesN, int tilesMN,
    long long aBatch, long long bBatch, long long cBatch, const float* __restrict__ rsum)
{
    constexpr int ABYTES = 256 * 128;
    constexpr int BUFB   = 2 * ABYTES;
    __shared__ __align__(1024) char lds[2 * BUFB];   // 128 KB

    const int tid = threadIdx.x;
    const int nwg = gridDim.x;
    const int bid = blockIdx.x;
    const int wgid = (bid & 7) * (nwg >> 3) + (bid >> 3);   // XCD swizzle
    const int bb  = wgid / tilesMN;
    const int rem = wgid % tilesMN;
    const int tm = rem / tilesN, tn = rem % tilesN;
    const int row0 = tm * 256, col0 = tn * 256;

    const h16* Ab = A + (long long)bb * aBatch;
    const h16* Bb = B + (long long)bb * bBatch;

    const int lane = tid & 63, wid = tid >> 6;
    const int wm = wid >> 2, wn = wid & 3;     // 2M x 4N, wave tile 128x64
    const int cl = lane & 31, half = lane >> 5;

    const int NT = K >> 6;

    f32x16 acc[4][2];
#pragma unroll
    for (int m = 0; m < 4; ++m)
#pragma unroll
        for (int n = 0; n < 2; ++n)
#pragma unroll
            for (int j = 0; j < 16; ++j) acc[m][n][j] = 0.f;

    char* l0 = (char*)lds;

    auto STAGE_B = [&](int kt, int buf) {
#pragma unroll
        for (int i = 0; i < 4; ++i) {
            int d = i * 512 + tid;
            int s = d & 7, r = d >> 3;
            int gg = s ^ (r & 7);
            gload16(Bb + (size_t)(col0 + r) * ldb + kt + gg * 8,
                    l0 + buf * BUFB + ABYTES + (r * 8 + s) * 16);
        }
    };
    auto STAGE_AH = [&](int kt, int buf, int mh) {
#pragma unroll
        for (int i = 0; i < 2; ++i) {
            int d = i * 512 + tid;
            int s = d & 7, hr = d >> 3;
            int r = ((hr & ~63) << 1) + mh * 64 + (hr & 63);
            int gg = s ^ (r & 7);
            gload16(Ab + (size_t)(row0 + r) * lda + kt + gg * 8,
                    l0 + buf * BUFB + (r * 8 + s) * 16);
        }
    };
    auto READ_A = [&](int buf, int mh, h16x8 (&af)[2][4]) {
#pragma unroll
        for (int fm = 0; fm < 2; ++fm)
#pragma unroll
            for (int ks = 0; ks < 4; ++ks) {
                int r = wm * 128 + (mh * 2 + fm) * 32 + cl;
                int s = (ks * 2 + half) ^ (r & 7);
                af[fm][ks] = *(const h16x8*)(l0 + buf * BUFB + (r * 8 + s) * 16);
            }
    };
    auto READ_B = [&](int buf, h16x8 (&bf)[2][4]) {
#pragma unroll
        for (int fn = 0; fn < 2; ++fn)
#pragma unroll
            for (int ks = 0; ks < 4; ++ks) {
                int r = wn * 64 + fn * 32 + cl;
                int s = (ks * 2 + half) ^ (r & 7);
                bf[fn][ks] = *(const h16x8*)(l0 + buf * BUFB + ABYTES + (r * 8 + s) * 16);
            }
    };
    auto MFMA_H = [&](int mh, h16x8 (&af)[2][4], h16x8 (&bf)[2][4]) {
        __builtin_amdgcn_s_setprio(1);
#pragma unroll
        for (int ks = 0; ks < 4; ++ks)
#pragma unroll
            for (int fm = 0; fm < 2; ++fm)
#pragma unroll
                for (int fn = 0; fn < 2; ++fn)
                    acc[mh * 2 + fm][fn] = __builtin_amdgcn_mfma_f32_32x32x16_f16(
                        af[fm][ks], bf[fn][ks], acc[mh * 2 + fm][fn], 0, 0, 0);
        __builtin_amdgcn_s_setprio(0);
    };

    STAGE_B(0, 0); STAGE_AH(0, 0, 0); STAGE_AH(0, 0, 1);
    asm volatile("s_waitcnt vmcnt(2)" ::: "memory");
    __builtin_amdgcn_s_barrier();

    h16x8 af[2][4], bf[2][4];

    for (int G = 0; G < NT; ++G) {
        const int buf = G & 1;
        const int kt1 = (G + 1) << 6;
        if (G + 1 < NT) {
            STAGE_B(kt1, buf ^ 1);
            STAGE_AH(kt1, buf ^ 1, 0);
            STAGE_AH(kt1, buf ^ 1, 1);
        }
        READ_A(buf, 0, af);
        READ_B(buf, bf);
        MFMA_H(0, af, bf);
        if (G + 1 < NT) asm volatile("s_waitcnt vmcnt(8)" ::: "memory");
        else            asm volatile("s_waitcnt vmcnt(0)" ::: "memory");
        __builtin_amdgcn_s_barrier();
        READ_A(buf, 1, af);
        MFMA_H(1, af, bf);
        if (G + 1 >= NT) break;
        asm volatile("s_waitcnt vmcnt(2)" ::: "memory");
        __builtin_amdgcn_s_barrier();
    }

    // ---- epilogue (32x32 C/D layout) ----
#pragma unroll
    for (int fm = 0; fm < 4; ++fm)
#pragma unroll
        for (int fn = 0; fn < 2; ++fn)
#pragma unroll
            for (int reg = 0; reg < 16; ++reg) {
                int rl  = (reg & 3) + 8 * (reg >> 2) + 4 * half;
                int row = row0 + wm * 128 + fm * 32 + rl;
                int col = col0 + wn * 64 + fn * 32 + cl;
                float vv = acc[fm][fn][reg];
                if constexpr (EPI == EPI_EXP) {
                    h16* C = (h16*)Cv + (long long)bb * cBatch;
                    C[(size_t)row * ldc + col] = (h16)__expf(vv - 16.0f);
                } else if constexpr (EPI == EPI_DIV) {
                    float* C = (float*)Cv + (long long)bb * cBatch;
                    C[(size_t)row * ldc + col] = vv * rsum[bb * SS + row];
                } else {
                    h16* C = (h16*)Cv + (long long)bb * cBatch;
                    C[(size_t)row * ldc + col] = (h16)vv;
                }
            }
}

// ==== small GEMM: 128x128 tile, 4 waves (2Mx2N), 256 thr, 64KB LDS ====
// 2 blocks/CU (m114 desync, round-6 proven) + 32x32x16 MFMA core.
template<int EPI>
__global__ __launch_bounds__(256, 2) void gemm32_sm(
    const h16* __restrict__ A, const h16* __restrict__ B, void* __restrict__ Cv,
    int lda, int ldb, int ldc, int K, int tilesN, int tilesMN,
    long long aBatch, long long bBatch, long long cBatch, const float* __restrict__ rsum)
{
    constexpr int ABYTES = 128 * 128;
    constexpr int BUFB   = 2 * ABYTES;
    __shared__ __align__(1024) char lds[2 * BUFB];   // 64 KB

    const int tid = threadIdx.x;
    const int nwg = gridDim.x;
    const int bid = blockIdx.x;
    const int wgid = (bid & 7) * (nwg >> 3) + (bid >> 3);
    const int bb  = wgid / tilesMN;
    const int rem = wgid % tilesMN;
    const int tm = rem / tilesN, tn = rem % tilesN;
    const int row0 = tm * 128, col0 = tn * 128;

    const h16* Ab = A + (long long)bb * aBatch;
    const h16* Bb = B + (long long)bb * bBatch;

    const int lane = tid & 63, wid = tid >> 6;
    const int wm = wid >> 1, wn = wid & 1;     // 2M x 2N, wave tile 64x64
    const int cl = lane & 31, half = lane >> 5;

    const int NT = K >> 6;

    f32x16 acc[2][2];
#pragma unroll
    for (int m = 0; m < 2; ++m)
#pragma unroll
        for (int n = 0; n < 2; ++n)
#pragma unroll
            for (int j = 0; j < 16; ++j) acc[m][n][j] = 0.f;

    char* l0 = (char*)lds;

    auto STAGE_B = [&](int kt, int buf) {
#pragma unroll
        for (int i = 0; i < 4; ++i) {
            int d = i * 256 + tid;
            int s = d & 7, r = d >> 3;
            int gg = s ^ (r & 7);
            gload16(Bb + (size_t)(col0 + r) * ldb + kt + gg * 8,
                    l0 + buf * BUFB + ABYTES + (r * 8 + s) * 16);
        }
    };
    auto STAGE_AH = [&](int kt, int buf, int mh) {
#pragma unroll
        for (int i = 0; i < 2; ++i) {
            int d = i * 256 + tid;
            int s = d & 7, hr = d >> 3;
            int r = ((hr & ~31) << 1) + mh * 32 + (hr & 31);
            int gg = s ^ (r & 7);
            gload16(Ab + (size_t)(row0 + r) * lda + kt + gg * 8,
                    l0 + buf * BUFB + (r * 8 + s) * 16);
        }
    };
    auto READ_A = [&](int buf, int mh, h16x8 (&af)[4]) {
#pragma unroll
        for (int ks = 0; ks < 4; ++ks) {
            int r = wm * 64 + mh * 32 + cl;
            int s = (ks * 2 + half) ^ (r & 7);
            af[ks] = *(const h16x8*)(l0 + buf * BUFB + (r * 8 + s) * 16);
        }
    };
    auto READ_B = [&](int buf, h16x8 (&bf)[2][4]) {
#pragma unroll
        for (int fn = 0; fn < 2; ++fn)
#pragma unroll
            for (int ks = 0; ks < 4; ++ks) {
                int r = wn * 64 + fn * 32 + cl;
                int s = (ks * 2 + half) ^ (r & 7);
                bf[fn][ks] = *(const h16x8*)(l0 + buf * BUFB + ABYTES + (r * 8 + s) * 16);
            }
    };
    auto MFMA_H = [&](int mh, h16x8 (&af)[4], h16x8 (&bf)[2][4]) {
        __builtin_amdgcn_s_setprio(1);
#pragma unroll
        for (int ks = 0; ks < 4; ++ks)
#pragma unroll
            for (int fn = 0; fn < 2; ++fn)
                acc[mh][fn] = __builtin_amdgcn_mfma_f32_32x32x16_f16(
                    af[ks], bf[fn][ks], acc[mh][fn], 0, 0, 0);
        __builtin_amdgcn_s_setprio(0);
    };

    STAGE_B(0, 0); STAGE_AH(0, 0, 0); STAGE_AH(0, 0, 1);
    asm volatile("s_waitcnt vmcnt(2)" ::: "memory");
    __builtin_amdgcn_s_barrier();

    h16x8 af[4], bf[2][4];

    for (int G = 0; G < NT; ++G) {
        const int buf = G & 1;
        const int kt1 = (G + 1) << 6;
        if (G + 1 < NT) {
            STAGE_B(kt1, buf ^ 1);
            STAGE_AH(kt1, buf ^ 1, 0);
            STAGE_AH(kt1, buf ^ 1, 1);
        }
        READ_A(buf, 0, af);
        READ_B(buf, bf);
        MFMA_H(0, af, bf);
        if (G + 1 < NT) asm volatile("s_waitcnt vmcnt(8)" ::: "memory");
        else            asm volatile("s_waitcnt vmcnt(0)" ::: "memory");
        __builtin_amdgcn_s_barrier();
        READ_A(buf, 1, af);
        MFMA_H(1, af, bf);
        if (G + 1 >= NT) break;
        asm volatile("s_waitcnt vmcnt(2)" ::: "memory");
        __builtin_amdgcn_s_barrier();
    }

    // ---- epilogue (32x32 C/D layout) ----
#pragma unroll
    for (int fm = 0; fm < 2; ++fm)
#pragma unroll
        for (int fn = 0; fn < 2; ++fn)
#pragma unroll
            for (int reg = 0; reg < 16; ++reg) {
                int rl  = (reg & 3) + 8 * (reg >> 2) + 4 * half;
                int row = row0 + wm * 64 + fm * 32 + rl;
                int col = col0 + wn * 64 + fn * 32 + cl;
                float vv = acc[fm][fn][reg];
                if constexpr (EPI == EPI_DIV) {
                    float* C = (float*)Cv + (long long)bb * cBatch;
                    C[(size_t)row * ldc + col] = vv * rsum[bb * SS + row];
                } else if constexpr (EPI == EPI_EXP) {
                    h16* C = (h16*)Cv + (long long)bb * cBatch;
                    C[(size_t)row * ldc + col] = (h16)__expf(vv - 16.0f);
                } else {
                    h16* C = (h16*)Cv + (long long)bb * cBatch;
                    C[(size_t)row * ldc + col] = (h16)vv;
                }
            }
}

// ---- reciprocal row sums of E (fp16 rows of length 2048); one block/row ----
__global__ __launch_bounds__(256) void rowsumE(const h16* __restrict__ sc,
                                               float* __restrict__ rsum) {
    const int row = blockIdx.x;
    const h16* rp = sc + (size_t)row * 2048;
    union { int4 i4; h16 h[8]; } u;
    u.i4 = ((const int4*)rp)[threadIdx.x];
    float s = 0.f;
#pragma unroll
    for (int j = 0; j < 8; ++j) s += (float)u.h[j];
#pragma unroll
    for (int off = 32; off; off >>= 1) s += __shfl_xor(s, off);
    __shared__ float ws[4];
    const int lane = threadIdx.x & 63, wid = threadIdx.x >> 6;
    if (lane == 0) ws[wid] = s;
    __syncthreads();
    if (threadIdx.x == 0)
        rsum[row] = 1.0f / (ws[0] + ws[1] + ws[2] + ws[3]);
}

extern "C" void kernel_launch(void* const* d_in, const int* in_sizes, int n_in,
                              void* d_out, int out_size, void* d_ws, size_t ws_size,
                              hipStream_t stream) {
    (void)in_sizes; (void)n_in; (void)out_size; (void)ws_size;
    const float* q = (const float*)d_in[0];
    const float* k = (const float*)d_in[1];
    const float* v = (const float*)d_in[2];
    const float* w = (const float*)d_in[3];
    float* out = (float*)d_out;

    const size_t QKV = (size_t)BB * SS * DD;
    h16* qh = (h16*)d_ws;            // 16 MB (reused as vpT after GEMM1 consumes q)
    h16* kh = qh + QKV;              // 16 MB
    h16* vh = kh + QKV;              // 16 MB
    h16* wh = vh + QKV;              // 2 MB
    h16* sc = wh + (size_t)DD * DD;  // E = exp(scores-16): 33.5 MB
    float* rsum = (float*)(sc + (size_t)BB * SS * SS);   // 32 KB reciprocal sums

    // 1) fused fp32 -> fp16 (scale 1/sqrt(64)=0.125 folded into q)
    cvt_all<<<6400, 256, 0, stream>>>(q, k, v, w, qh, kh, vh, wh);

    // 2) GEMM1 + exp epilogue: E[b][q][k] = exp(sum_d qh*kh - 16)
    //    M=N=2048, K=1024/batch; 256x256 tiles: 8x8x4 = 256 wgs
    gemm32_big<EPI_EXP><<<256, 512, 0, stream>>>(
        qh, kh, (void*)sc, DD, DD, SS, DD, 8, 64,
        (long long)SS * DD, (long long)SS * DD, (long long)SS * SS, nullptr);

    // 3) reciprocal row sums (read-only; replaces in-place softmax)
    rowsumE<<<BB * SS, 256, 0, stream>>>(sc, rsum);

    // 4) GEMM2: vpT[e][s] = sum_d W[e,d]*V[s,d]; M=1024, N=8192, K=1024.
    //    128^2 tiles: 8x64 = 512 wgs
    h16* vpT = qh;
    gemm32_sm<EPI_H16><<<512, 256, 0, stream>>>(
        wh, vh, (void*)vpT, DD, DD, BB * SS, DD, 64, 512,
        0LL, 0LL, 0LL, nullptr);

    // 5) GEMM3 + normalize: Y[b][q][e] = (sum_k E[b,q,k]*vpT[e, b*2048+k]) * rsum[b,q]
    //    M=2048/batch, N=1024, K=2048. 128^2 tiles: 16x8x4 = 512 wgs
    gemm32_sm<EPI_DIV><<<512, 256, 0, stream>>>(
        sc, vpT, (void*)out, SS, BB * SS, DD, SS, 8, 128,
        (long long)SS * SS, (long long)SS, (long long)SS * DD, rsum);
}

// Round 12
// 134.334 us; speedup vs baseline: 1.2222x; 1.0937x over previous
//
#include <hip/hip_runtime.h>
#include <hip/hip_fp16.h>
#include <stdint.h>

// ---- types ----
typedef _Float16 h16;
typedef _Float16 h16x8 __attribute__((ext_vector_type(8)));
typedef float f32x4 __attribute__((ext_vector_type(4)));

#define BB 4
#define SS 2048
#define DD 1024

// epilogue modes
#define EPI_H16 0   // store fp16 C
#define EPI_EXP 1   // store fp16 exp(C - 16)   (unnormalized softmax numerator)
#define EPI_DIV 2   // store fp32 C * rsum[row] (rsum = reciprocal row sums)

__device__ __forceinline__ void gload16(const void* g, void* l) {
    __builtin_amdgcn_global_load_lds(
        (const __attribute__((address_space(1))) uint32_t*)g,
        (__attribute__((address_space(3))) uint32_t*)l, 16, 0, 0);
}

// ---- fused fp32 -> fp16 convert; every instruction wave-coalesced ----
__global__ __launch_bounds__(256) void cvt_all(
    const float* __restrict__ q, const float* __restrict__ k,
    const float* __restrict__ v, const float* __restrict__ w,
    h16* __restrict__ qh, h16* __restrict__ kh,
    h16* __restrict__ vh, h16* __restrict__ wh) {
    int b = blockIdx.x;
    const float* src; h16* dst; float sc = 1.0f;
    if (b < 2048)      { src = q; dst = qh; sc = 0.125f; }
    else if (b < 4096) { src = k; dst = kh; b -= 2048; }
    else if (b < 6144) { src = v; dst = vh; b -= 4096; }
    else               { src = w; dst = wh; b -= 6144; }
    size_t base = (size_t)b * 1024 + threadIdx.x;   // float4 index
#pragma unroll
    for (int i = 0; i < 4; ++i) {
        size_t g = base + (size_t)i * 256;
        float4 a = ((const float4*)src)[g];
        union { int2 i2; h16 h[4]; } u;
        u.h[0] = (h16)(a.x * sc); u.h[1] = (h16)(a.y * sc);
        u.h[2] = (h16)(a.z * sc); u.h[3] = (h16)(a.w * sc);
        ((int2*)dst)[g] = u.i2;
    }
}

// ==== 2-phase bt-form GEMM, BM=256/BN=256, 8 waves, 1 block/CU ====
// (round-5 verified kernel; EPI epilogue added — elementwise only)
template<int BM, int EPI>
__global__ __launch_bounds__(512, 2) void gemm2p(
    const h16* __restrict__ A, const h16* __restrict__ B, void* __restrict__ Cv,
    int lda, int ldb, int ldc, int K, int tilesN, int tilesMN,
    long long aBatch, long long bBatch, long long cBatch, const float* __restrict__ rsum)
{
    constexpr int WROWS  = BM / 2;
    constexpr int MF     = WROWS / 16;
    constexpr int MH     = MF / 2;
    constexpr int AH     = WROWS / 2;
    constexpr int AL     = BM / 128;
    constexpr int ABYTES = BM * 128;
    constexpr int BBYTES = 256 * 128;
    constexpr int BUFB   = ABYTES + BBYTES;

    __shared__ __align__(1024) char lds[2 * BUFB];

    const int tid = threadIdx.x;
    const int nwg = gridDim.x;
    const int bid = blockIdx.x;
    const int wgid = (bid & 7) * (nwg >> 3) + (bid >> 3);
    const int bb  = wgid / tilesMN;
    const int rem = wgid % tilesMN;
    const int tm = rem / tilesN, tn = rem % tilesN;
    const int row0 = tm * BM, col0 = tn * 256;

    const h16* Ab = A + (long long)bb * aBatch;
    const h16* Bb = B + (long long)bb * bBatch;

    const int lane = tid & 63, wid = tid >> 6;
    const int wm = wid >> 2, wn = wid & 3;
    const int frow = lane & 15, kq = lane >> 4;

    const int NT = K >> 6;

    f32x4 acc[MF][4];
#pragma unroll
    for (int m = 0; m < MF; ++m)
#pragma unroll
        for (int n = 0; n < 4; ++n) acc[m][n] = (f32x4){0.f, 0.f, 0.f, 0.f};

    char* l0 = (char*)lds;

    auto STAGE_B = [&](int kt, int buf) {
#pragma unroll
        for (int i = 0; i < 4; ++i) {
            int d = i * 512 + tid;
            int s = d & 7, r = d >> 3;
            int gg = s ^ (r & 7);
            gload16(Bb + (size_t)(col0 + r) * ldb + kt + gg * 8,
                    l0 + buf * BUFB + ABYTES + (r * 8 + s) * 16);
        }
    };
    auto STAGE_AH = [&](int kt, int buf, int mh) {
#pragma unroll
        for (int i = 0; i < AL; ++i) {
            int d = i * 512 + tid;
            int s = d & 7, hr = d >> 3;
            int r = ((hr & ~(AH - 1)) << 1) + mh * AH + (hr & (AH - 1));
            int gg = s ^ (r & 7);
            gload16(Ab + (size_t)(row0 + r) * lda + kt + gg * 8,
                    l0 + buf * BUFB + (r * 8 + s) * 16);
        }
    };
    auto READ_A = [&](int buf, int mh, h16x8 (&af)[MH][2]) {
#pragma unroll
        for (int mm = 0; mm < MH; ++mm)
#pragma unroll
            for (int ks = 0; ks < 2; ++ks) {
                int r = wm * WROWS + (mh * MH + mm) * 16 + frow;
                int s = (ks * 4 + kq) ^ (r & 7);
                af[mm][ks] = *(const h16x8*)(l0 + buf * BUFB + (r * 8 + s) * 16);
            }
    };
    auto READ_B = [&](int buf, h16x8 (&bf)[4][2]) {
#pragma unroll
        for (int nn = 0; nn < 4; ++nn)
#pragma unroll
            for (int ks = 0; ks < 2; ++ks) {
                int r = wn * 64 + nn * 16 + frow;
                int s = (ks * 4 + kq) ^ (r & 7);
                bf[nn][ks] = *(const h16x8*)(l0 + buf * BUFB + ABYTES + (r * 8 + s) * 16);
            }
    };
    auto MFMA_H = [&](int mh, h16x8 (&af)[MH][2], h16x8 (&bf)[4][2]) {
        __builtin_amdgcn_s_setprio(1);
#pragma unroll
        for (int ks = 0; ks < 2; ++ks)
#pragma unroll
            for (int mm = 0; mm < MH; ++mm)
#pragma unroll
                for (int nn = 0; nn < 4; ++nn)
                    acc[mh * MH + mm][nn] =
                        __builtin_amdgcn_mfma_f32_16x16x32_f16(
                            af[mm][ks], bf[nn][ks], acc[mh * MH + mm][nn], 0, 0, 0);
        __builtin_amdgcn_s_setprio(0);
    };

    STAGE_B(0, 0); STAGE_AH(0, 0, 0); STAGE_AH(0, 0, 1);
    if constexpr (BM == 256) asm volatile("s_waitcnt vmcnt(2)" ::: "memory");
    else                     asm volatile("s_waitcnt vmcnt(1)" ::: "memory");
    __builtin_amdgcn_s_barrier();

    h16x8 af[MH][2], bf[4][2];

    for (int G = 0; G < NT; ++G) {
        const int buf = G & 1;
        const int kt1 = (G + 1) << 6;
        if (G + 1 < NT) {
            STAGE_B(kt1, buf ^ 1);
            STAGE_AH(kt1, buf ^ 1, 0);
            STAGE_AH(kt1, buf ^ 1, 1);
        }
        READ_A(buf, 0, af);
        READ_B(buf, bf);
        MFMA_H(0, af, bf);
        if (G + 1 < NT) {
            if constexpr (BM == 256) asm volatile("s_waitcnt vmcnt(8)" ::: "memory");
            else                     asm volatile("s_waitcnt vmcnt(6)" ::: "memory");
        } else {
            asm volatile("s_waitcnt vmcnt(0)" ::: "memory");
        }
        __builtin_amdgcn_s_barrier();
        READ_A(buf, 1, af);
        MFMA_H(1, af, bf);
        if (G + 1 >= NT) break;
        if constexpr (BM == 256) asm volatile("s_waitcnt vmcnt(2)" ::: "memory");
        else                     asm volatile("s_waitcnt vmcnt(1)" ::: "memory");
        __builtin_amdgcn_s_barrier();
    }

    // ---- epilogue: C/D layout col=lane&15, row=(lane>>4)*4+j
    const int erow = row0 + wm * WROWS + (lane >> 4) * 4;
    const int ecol = col0 + wn * 64 + (lane & 15);
#pragma unroll
    for (int m = 0; m < MF; ++m)
#pragma unroll
        for (int n = 0; n < 4; ++n)
#pragma unroll
            for (int j = 0; j < 4; ++j) {
                int row = erow + m * 16 + j, col = ecol + n * 16;
                float vv = acc[m][n][j];
                if constexpr (EPI == EPI_EXP) {
                    h16* C = (h16*)Cv + (long long)bb * cBatch;
                    C[(size_t)row * ldc + col] = (h16)__expf(vv - 16.0f);
                } else if constexpr (EPI == EPI_DIV) {
                    float* C = (float*)Cv + (long long)bb * cBatch;
                    C[(size_t)row * ldc + col] = vv * rsum[bb * SS + row];
                } else {
                    h16* C = (h16*)Cv + (long long)bb * cBatch;
                    C[(size_t)row * ldc + col] = (h16)vv;
                }
            }
}

// ==== small GEMM: 128x128 tile, 4 waves (2Mx2N), 256 thr, 64KB LDS ====
// 2 blocks/CU (round-6 verified kernel; EPI epilogue added)
template<int EPI>
__global__ __launch_bounds__(256, 2) void gemm2p_sm(
    const h16* __restrict__ A, const h16* __restrict__ B, void* __restrict__ Cv,
    int lda, int ldb, int ldc, int K, int tilesN, int tilesMN,
    long long aBatch, long long bBatch, long long cBatch, const float* __restrict__ rsum)
{
    constexpr int ABYTES = 128 * 128;
    constexpr int BBYTES = 128 * 128;
    constexpr int BUFB   = ABYTES + BBYTES;

    __shared__ __align__(1024) char lds[2 * BUFB];   // 64 KB

    const int tid = threadIdx.x;
    const int nwg = gridDim.x;
    const int bid = blockIdx.x;
    const int wgid = (bid & 7) * (nwg >> 3) + (bid >> 3);   // XCD swizzle
    const int bb  = wgid / tilesMN;
    const int rem = wgid % tilesMN;
    const int tm = rem / tilesN, tn = rem % tilesN;
    const int row0 = tm * 128, col0 = tn * 128;

    const h16* Ab = A + (long long)bb * aBatch;
    const h16* Bb = B + (long long)bb * bBatch;

    const int lane = tid & 63, wid = tid >> 6;
    const int wm = wid >> 1, wn = wid & 1;     // 2M x 2N, wave tile 64x64
    const int frow = lane & 15, kq = lane >> 4;

    const int NT = K >> 6;

    f32x4 acc[4][4];
#pragma unroll
    for (int m = 0; m < 4; ++m)
#pragma unroll
        for (int n = 0; n < 4; ++n) acc[m][n] = (f32x4){0.f, 0.f, 0.f, 0.f};

    char* l0 = (char*)lds;

    auto STAGE_B = [&](int kt, int buf) {
#pragma unroll
        for (int i = 0; i < 4; ++i) {
            int d = i * 256 + tid;
            int s = d & 7, r = d >> 3;
            int gg = s ^ (r & 7);
            gload16(Bb + (size_t)(col0 + r) * ldb + kt + gg * 8,
                    l0 + buf * BUFB + ABYTES + (r * 8 + s) * 16);
        }
    };
    auto STAGE_AH = [&](int kt, int buf, int mh) {
#pragma unroll
        for (int i = 0; i < 2; ++i) {
            int d = i * 256 + tid;
            int s = d & 7, hr = d >> 3;
            int r = ((hr & ~31) << 1) + mh * 32 + (hr & 31);
            int gg = s ^ (r & 7);
            gload16(Ab + (size_t)(row0 + r) * lda + kt + gg * 8,
                    l0 + buf * BUFB + (r * 8 + s) * 16);
        }
    };
    auto READ_A = [&](int buf, int mh, h16x8 (&af)[2][2]) {
#pragma unroll
        for (int mm = 0; mm < 2; ++mm)
#pragma unroll
            for (int ks = 0; ks < 2; ++ks) {
                int r = wm * 64 + (mh * 2 + mm) * 16 + frow;
                int s = (ks * 4 + kq) ^ (r & 7);
                af[mm][ks] = *(const h16x8*)(l0 + buf * BUFB + (r * 8 + s) * 16);
            }
    };
    auto READ_B = [&](int buf, h16x8 (&bf)[4][2]) {
#pragma unroll
        for (int nn = 0; nn < 4; ++nn)
#pragma unroll
            for (int ks = 0; ks < 2; ++ks) {
                int r = wn * 64 + nn * 16 + frow;
                int s = (ks * 4 + kq) ^ (r & 7);
                bf[nn][ks] = *(const h16x8*)(l0 + buf * BUFB + ABYTES + (r * 8 + s) * 16);
            }
    };
    auto MFMA_H = [&](int mh, h16x8 (&af)[2][2], h16x8 (&bf)[4][2]) {
        __builtin_amdgcn_s_setprio(1);
#pragma unroll
        for (int ks = 0; ks < 2; ++ks)
#pragma unroll
            for (int mm = 0; mm < 2; ++mm)
#pragma unroll
                for (int nn = 0; nn < 4; ++nn)
                    acc[mh * 2 + mm][nn] =
                        __builtin_amdgcn_mfma_f32_16x16x32_f16(
                            af[mm][ks], bf[nn][ks], acc[mh * 2 + mm][nn], 0, 0, 0);
        __builtin_amdgcn_s_setprio(0);
    };

    STAGE_B(0, 0); STAGE_AH(0, 0, 0); STAGE_AH(0, 0, 1);
    asm volatile("s_waitcnt vmcnt(2)" ::: "memory");
    __builtin_amdgcn_s_barrier();

    h16x8 af[2][2], bf[4][2];

    for (int G = 0; G < NT; ++G) {
        const int buf = G & 1;
        const int kt1 = (G + 1) << 6;
        if (G + 1 < NT) {
            STAGE_B(kt1, buf ^ 1);
            STAGE_AH(kt1, buf ^ 1, 0);
            STAGE_AH(kt1, buf ^ 1, 1);
        }
        READ_A(buf, 0, af);
        READ_B(buf, bf);
        MFMA_H(0, af, bf);
        if (G + 1 < NT) asm volatile("s_waitcnt vmcnt(8)" ::: "memory");
        else            asm volatile("s_waitcnt vmcnt(0)" ::: "memory");
        __builtin_amdgcn_s_barrier();
        READ_A(buf, 1, af);
        MFMA_H(1, af, bf);
        if (G + 1 >= NT) break;
        asm volatile("s_waitcnt vmcnt(2)" ::: "memory");
        __builtin_amdgcn_s_barrier();
    }

    const int erow = row0 + wm * 64 + (lane >> 4) * 4;
    const int ecol = col0 + wn * 64 + (lane & 15);
#pragma unroll
    for (int m = 0; m < 4; ++m)
#pragma unroll
        for (int n = 0; n < 4; ++n)
#pragma unroll
            for (int j = 0; j < 4; ++j) {
                int row = erow + m * 16 + j, col = ecol + n * 16;
                float vv = acc[m][n][j];
                if constexpr (EPI == EPI_DIV) {
                    float* C = (float*)Cv + (long long)bb * cBatch;
                    C[(size_t)row * ldc + col] = vv * rsum[bb * SS + row];
                } else if constexpr (EPI == EPI_EXP) {
                    h16* C = (h16*)Cv + (long long)bb * cBatch;
                    C[(size_t)row * ldc + col] = (h16)__expf(vv - 16.0f);
                } else {
                    h16* C = (h16*)Cv + (long long)bb * cBatch;
                    C[(size_t)row * ldc + col] = (h16)vv;
                }
            }
}

// ---- reciprocal row sums of E (fp16 rows of length 2048); one block/row ----
__global__ __launch_bounds__(256) void rowsumE(const h16* __restrict__ sc,
                                               float* __restrict__ rsum) {
    const int row = blockIdx.x;
    const h16* rp = sc + (size_t)row * 2048;
    union { int4 i4; h16 h[8]; } u;
    u.i4 = ((const int4*)rp)[threadIdx.x];
    float s = 0.f;
#pragma unroll
    for (int j = 0; j < 8; ++j) s += (float)u.h[j];
#pragma unroll
    for (int off = 32; off; off >>= 1) s += __shfl_xor(s, off);
    __shared__ float ws[4];
    const int lane = threadIdx.x & 63, wid = threadIdx.x >> 6;
    if (lane == 0) ws[wid] = s;
    __syncthreads();
    if (threadIdx.x == 0)
        rsum[row] = 1.0f / (ws[0] + ws[1] + ws[2] + ws[3]);
}

extern "C" void kernel_launch(void* const* d_in, const int* in_sizes, int n_in,
                              void* d_out, int out_size, void* d_ws, size_t ws_size,
                              hipStream_t stream) {
    (void)in_sizes; (void)n_in; (void)out_size; (void)ws_size;
    const float* q = (const float*)d_in[0];
    const float* k = (const float*)d_in[1];
    const float* v = (const float*)d_in[2];
    const float* w = (const float*)d_in[3];
    float* out = (float*)d_out;

    const size_t QKV = (size_t)BB * SS * DD;
    h16* qh = (h16*)d_ws;            // 16 MB (reused as vpT after GEMM1 consumes q)
    h16* kh = qh + QKV;              // 16 MB
    h16* vh = kh + QKV;              // 16 MB
    h16* wh = vh + QKV;              // 2 MB
    h16* sc = wh + (size_t)DD * DD;  // E = exp(scores-16): 33.5 MB
    float* rsum = (float*)(sc + (size_t)BB * SS * SS);   // 32 KB reciprocal sums

    // 1) fused fp32 -> fp16 (scale 1/sqrt(64)=0.125 folded into q)
    cvt_all<<<6400, 256, 0, stream>>>(q, k, v, w, qh, kh, vh, wh);

    // 2) GEMM1 + exp epilogue: E[b][q][k] = exp(sum_d qh*kh - 16)
    //    256x256 tiles: 8x8x4 = 256 wgs (1 block/CU)
    gemm2p<256, EPI_EXP><<<256, 512, 0, stream>>>(
        qh, kh, (void*)sc, DD, DD, SS, DD, /*tilesN=*/8, /*tilesMN=*/64,
        (long long)SS * DD, (long long)SS * DD, (long long)SS * SS, nullptr);

    // 3) reciprocal row sums (read-only; replaces in-place softmax)
    rowsumE<<<BB * SS, 256, 0, stream>>>(sc, rsum);

    // 4) GEMM2: vpT[e][s] = sum_d W[e,d]*V[s,d]; M=1024, N=8192, K=1024.
    //    128^2 tiles: 8x64 = 512 wgs, 2 blocks/CU
    h16* vpT = qh;
    gemm2p_sm<EPI_H16><<<512, 256, 0, stream>>>(
        wh, vh, (void*)vpT, DD, DD, BB * SS, DD, /*tilesN=*/64, /*tilesMN=*/512,
        0LL, 0LL, 0LL, nullptr);

    // 5) GEMM3 + normalize: Y[b][q][e] = (sum_k E*vpT) * rsum[b,q]
    //    M=2048/batch, N=1024, K=2048. 128^2 tiles: 16x8x4 = 512 wgs
    gemm2p_sm<EPI_DIV><<<512, 256, 0, stream>>>(
        sc, vpT, (void*)out, SS, BB * SS, DD, SS, /*tilesN=*/8, /*tilesMN=*/128,
        (long long)SS * SS, (long long)SS, (long long)SS * DD, rsum);
}